// Round 8
// baseline (47.665 us; speedup 1.0000x reference)
//
#include <hip/hip_runtime.h>
#include <math.h>

#define NSEG 4096
#define DD   128
#define NEG  (-1e30f)

typedef float f4 __attribute__((ext_vector_type(4)));

// Wave-parallel dual lower_bound over sorted seg[0..N):
//   lanes 0-31 search target g, lanes 32-63 search target g+1.
// 32-ary bracketing: each round 32 probes shrink the range 32x
// (500000 -> 15625 -> 489 -> 16 -> final), so the dependent-load chain is
// 4 loads instead of 2x19 scalar ones. Uniform control flow, OOB-safe.
__device__ __forceinline__ void wave_bounds(const int* __restrict__ seg, int N, int g,
                                            int& s_out, int& e_out) {
    int lane = threadIdx.x & 63;
    int half = lane >> 5;
    int l32  = lane & 31;
    int target = g + half;
    int lo = 0;
    int range = N;                                  // invariant: answer in [lo, lo+range]
    while (range > 32) {
        int chunk = (range + 31) >> 5;
        int p = min(lo + (l32 + 1) * chunk - 1, N - 1);
        bool cond = (seg[p] < target);              // prefix of 1s within the half
        unsigned long long b = __ballot(cond);
        int cnt = half ? __popcll(b >> 32) : __popcll(b & 0xFFFFFFFFull);
        lo = min(lo + cnt * chunk, N);
        range = chunk;
    }
    {   // final: probe lo..lo+31 (covers range <= 32; cnt==32 -> lo+32)
        int p = lo + l32;
        bool cond = (p < N) && (seg[p] < target);
        unsigned long long b = __ballot(cond);
        int cnt = half ? __popcll(b >> 32) : __popcll(b & 0xFFFFFFFFull);
        lo += cnt;
    }
    s_out = __shfl(lo, 0);
    e_out = __shfl(lo, 32);
}

// ---------------- single fused kernel: bounds + gate + online softmax + readout ----------------
// One 256-thread block per segment. Each 32-lane row-group keeps a PRIVATE
// online-softmax state (m, l, acc); the 8 group states merge once at the end.
// Main loop has NO barriers and FULLY UNIFORM control flow: all loads are
// unconditional with row index clamped to e-1 (always in-bounds); row
// validity is per-lane selects only. Invalid rows carry gate NEG so their
// softmax weight exp(NEG - m) == 0 exactly; never-valid groups are cancelled
// at the merge by weight exp(NEG - M) == 0.
__global__ __launch_bounds__(256) void fused_kernel(
        const float* __restrict__ feat,
        const float* __restrict__ gw,
        const float* __restrict__ gb,
        const int*  __restrict__ seg,
        int N,
        float* __restrict__ out) {
    __shared__ f4    red[8][32];
    __shared__ float mred[8];
    __shared__ float lred[8];

    int g = blockIdx.x;
    int tid = threadIdx.x;
    int rg  = tid >> 5;     // row group 0..7
    int c   = tid & 31;     // float4 column

    int s, e;
    wave_bounds(seg, N, g, s, e);           // every wave computes the same -> no barrier
    int len = e - s;

    if (len <= 0) {                          // uniform per block -> legal early-out
        if (rg == 0) ((f4*)out)[g * 32 + c] = (f4){0.f, 0.f, 0.f, 0.f};
        return;
    }

    const f4* fp = (const f4*)feat;
    f4    w4 = ((const f4*)gw)[c];
    float b0 = gb[0];

    float m = NEG, l = 0.0f;
    f4 acc = {0.f, 0.f, 0.f, 0.f};

    int ntiles = (len + 31) >> 5;
    int emax = e - 1;                        // >= s since len > 0

    // prefetch tile 0 (rows s+rg+8k, k=0..3), clamped -> always in-bounds
    int n0 = s + rg;
    f4 nv0 = __builtin_nontemporal_load(&fp[min(n0,      emax) * 32 + c]);
    f4 nv1 = __builtin_nontemporal_load(&fp[min(n0 + 8,  emax) * 32 + c]);
    f4 nv2 = __builtin_nontemporal_load(&fp[min(n0 + 16, emax) * 32 + c]);
    f4 nv3 = __builtin_nontemporal_load(&fp[min(n0 + 24, emax) * 32 + c]);

    for (int t = 0; t < ntiles; ++t) {
        int r0 = s + t * 32 + rg;
        f4 c0 = nv0, c1 = nv1, c2 = nv2, c3 = nv3;

        // prefetch next tile: unconditional clamped loads (no divergence)
        int p0 = r0 + 32;
        nv0 = __builtin_nontemporal_load(&fp[min(p0,      emax) * 32 + c]);
        nv1 = __builtin_nontemporal_load(&fp[min(p0 + 8,  emax) * 32 + c]);
        nv2 = __builtin_nontemporal_load(&fp[min(p0 + 16, emax) * 32 + c]);
        nv3 = __builtin_nontemporal_load(&fp[min(p0 + 24, emax) * 32 + c]);

        // gate dots for this thread's 4 rows; butterfly across the 32-lane group
        float d0 = c0.x*w4.x + c0.y*w4.y + c0.z*w4.z + c0.w*w4.w;
        float d1 = c1.x*w4.x + c1.y*w4.y + c1.z*w4.z + c1.w*w4.w;
        float d2 = c2.x*w4.x + c2.y*w4.y + c2.z*w4.z + c2.w*w4.w;
        float d3 = c3.x*w4.x + c3.y*w4.y + c3.z*w4.z + c3.w*w4.w;
        #pragma unroll
        for (int off = 16; off; off >>= 1) {
            d0 += __shfl_xor(d0, off);
            d1 += __shfl_xor(d1, off);
            d2 += __shfl_xor(d2, off);
            d3 += __shfl_xor(d3, off);
        }
        // validity via per-lane selects only
        float g0 = (r0      < e) ? d0 + b0 : NEG;
        float g1 = (r0 + 8  < e) ? d1 + b0 : NEG;
        float g2 = (r0 + 16 < e) ? d2 + b0 : NEG;
        float g3 = (r0 + 24 < e) ? d3 + b0 : NEG;

        // group-private online softmax update (pure VALU)
        float m_new = fmaxf(m, fmaxf(fmaxf(g0, g1), fmaxf(g2, g3)));
        float scale = __expf(m - m_new);      // all-finite arguments
        float p0w = __expf(g0 - m_new);       // invalid row: exp(~-1e30) == 0 exactly,
        float p1w = __expf(g1 - m_new);       //  so clamped (real) data adds 0
        float p2w = __expf(g2 - m_new);
        float p3w = __expf(g3 - m_new);
        l = l * scale + (p0w + p1w) + (p2w + p3w);
        acc = acc * scale + p0w * c0 + p1w * c1 + p2w * c2 + p3w * c3;
        m = m_new;
        // never-valid group: m stays NEG, p == 1, acc accumulates real rows —
        // cancelled exactly at merge by weight exp(NEG - M) == 0.
    }

    // merge the 8 group states: M = max m_k; out = sum exp(m_k-M)*acc_k / sum exp(m_k-M)*l_k
    red[rg][c] = acc;
    if (c == 0) { mred[rg] = m; lred[rg] = l; }
    __syncthreads();
    if (rg == 0) {
        float M = mred[0];
        #pragma unroll
        for (int k = 1; k < 8; ++k) M = fmaxf(M, mred[k]);
        f4 r = {0.f, 0.f, 0.f, 0.f};
        float ltot = 0.0f;
        #pragma unroll
        for (int k = 0; k < 8; ++k) {
            float wgt = __expf(mred[k] - M);
            ltot += lred[k] * wgt;
            r += wgt * red[k][c];
        }
        float invl = 1.0f / ltot;            // len > 0: group with global max has wgt 1, l >= 1
        r *= invl;
        ((f4*)out)[g * 32 + c] = r;
    }
}

// ---------------- launch ----------------
extern "C" void kernel_launch(void* const* d_in, const int* in_sizes, int n_in,
                              void* d_out, int out_size, void* d_ws, size_t ws_size,
                              hipStream_t stream) {
    const float* feat = (const float*)d_in[0];
    const float* gw   = (const float*)d_in[1];
    const float* gb   = (const float*)d_in[2];
    const int*   seg  = (const int*)d_in[3];
    int N = in_sizes[0] / DD;                        // 500000

    fused_kernel<<<NSEG, 256, 0, stream>>>(feat, gw, gb, seg, N, (float*)d_out);
}

// Round 9
// 46.565 us; speedup vs baseline: 1.0236x; 1.0236x over previous
//
#include <hip/hip_runtime.h>
#include <math.h>

#define NSEG 4096
#define DD   128
#define NEG  (-1e30f)

typedef float f4 __attribute__((ext_vector_type(4)));

// Prior-seeded lower_bound over sorted seg[0..N): first index n with seg[n] >= tgt.
// Seed window +-3000 around the uniform prior (binomial sd ~353 rows); the two
// bracket guards are INDEPENDENT loads that PROVE containment (sorted array),
// with a full-range fallback -> always correct, deterministic. Chain ~1+13
// dependent loads instead of 19.
__device__ __forceinline__ int lower_bound_seeded(const int* __restrict__ seg, int N,
                                                  int tgt, int prior) {
    int lo = max(0, prior - 3000);
    int hi = min(N, prior + 3000);
    if (lo > 0 && !(seg[lo - 1] < tgt)) lo = 0;   // bracket guard (left)
    if (hi < N && !(seg[hi] >= tgt))    hi = N;   // bracket guard (right)
    while (lo < hi) {
        int mid = (lo + hi) >> 1;
        if (seg[mid] < tgt) lo = mid + 1; else hi = mid;
    }
    return lo;
}

// ---------------- single fused kernel: bounds + gate + online softmax + readout ----------------
// One 256-thread block per segment. Each 32-lane row-group keeps a PRIVATE
// online-softmax state (m, l, acc); the 8 group states merge once at the end.
// Main loop has NO barriers and FULLY UNIFORM control flow: all loads are
// unconditional with row index clamped to e-1 (always in-bounds); row
// validity is per-lane selects only. Invalid rows carry gate NEG so their
// softmax weight exp(NEG - m) == 0 exactly; never-valid groups are cancelled
// at the merge by weight exp(NEG - M) == 0.
__global__ __launch_bounds__(256) void fused_kernel(
        const float* __restrict__ feat,
        const float* __restrict__ gw,
        const float* __restrict__ gb,
        const int*  __restrict__ seg,
        int N,
        float* __restrict__ out) {
    __shared__ f4    red[8][32];
    __shared__ float mred[8];
    __shared__ float lred[8];

    int g = blockIdx.x;
    int tid = threadIdx.x;
    int rg  = tid >> 5;     // row group 0..7
    int c   = tid & 31;     // float4 column

    // two independent seeded searches; compiler ILP-overlaps the probe chains
    int prior = (int)(((long long)g * N) / NSEG);
    int s = lower_bound_seeded(seg, N, g,     prior);
    int e = lower_bound_seeded(seg, N, g + 1, prior);
    int len = e - s;

    if (len <= 0) {                          // uniform per block -> legal early-out
        if (rg == 0) ((f4*)out)[g * 32 + c] = (f4){0.f, 0.f, 0.f, 0.f};
        return;
    }

    const f4* fp = (const f4*)feat;
    f4    w4 = ((const f4*)gw)[c];
    float b0 = gb[0];

    float m = NEG, l = 0.0f;
    f4 acc = {0.f, 0.f, 0.f, 0.f};

    int ntiles = (len + 31) >> 5;
    int emax = e - 1;                        // >= s since len > 0

    // prefetch tile 0 (rows s+rg+8k, k=0..3), clamped -> always in-bounds
    int n0 = s + rg;
    f4 nv0 = __builtin_nontemporal_load(&fp[min(n0,      emax) * 32 + c]);
    f4 nv1 = __builtin_nontemporal_load(&fp[min(n0 + 8,  emax) * 32 + c]);
    f4 nv2 = __builtin_nontemporal_load(&fp[min(n0 + 16, emax) * 32 + c]);
    f4 nv3 = __builtin_nontemporal_load(&fp[min(n0 + 24, emax) * 32 + c]);

    for (int t = 0; t < ntiles; ++t) {
        int r0 = s + t * 32 + rg;
        f4 c0 = nv0, c1 = nv1, c2 = nv2, c3 = nv3;

        // prefetch next tile: unconditional clamped loads (no divergence)
        int p0 = r0 + 32;
        nv0 = __builtin_nontemporal_load(&fp[min(p0,      emax) * 32 + c]);
        nv1 = __builtin_nontemporal_load(&fp[min(p0 + 8,  emax) * 32 + c]);
        nv2 = __builtin_nontemporal_load(&fp[min(p0 + 16, emax) * 32 + c]);
        nv3 = __builtin_nontemporal_load(&fp[min(p0 + 24, emax) * 32 + c]);

        // gate dots for this thread's 4 rows; butterfly across the 32-lane group
        float d0 = c0.x*w4.x + c0.y*w4.y + c0.z*w4.z + c0.w*w4.w;
        float d1 = c1.x*w4.x + c1.y*w4.y + c1.z*w4.z + c1.w*w4.w;
        float d2 = c2.x*w4.x + c2.y*w4.y + c2.z*w4.z + c2.w*w4.w;
        float d3 = c3.x*w4.x + c3.y*w4.y + c3.z*w4.z + c3.w*w4.w;
        #pragma unroll
        for (int off = 16; off; off >>= 1) {
            d0 += __shfl_xor(d0, off);
            d1 += __shfl_xor(d1, off);
            d2 += __shfl_xor(d2, off);
            d3 += __shfl_xor(d3, off);
        }
        // validity via per-lane selects only
        float g0 = (r0      < e) ? d0 + b0 : NEG;
        float g1 = (r0 + 8  < e) ? d1 + b0 : NEG;
        float g2 = (r0 + 16 < e) ? d2 + b0 : NEG;
        float g3 = (r0 + 24 < e) ? d3 + b0 : NEG;

        // group-private online softmax update (pure VALU)
        float m_new = fmaxf(m, fmaxf(fmaxf(g0, g1), fmaxf(g2, g3)));
        float scale = __expf(m - m_new);      // all-finite arguments
        float p0w = __expf(g0 - m_new);       // invalid row: exp(~-1e30) == 0 exactly,
        float p1w = __expf(g1 - m_new);       //  so clamped (real) data adds 0
        float p2w = __expf(g2 - m_new);
        float p3w = __expf(g3 - m_new);
        l = l * scale + (p0w + p1w) + (p2w + p3w);
        acc = acc * scale + p0w * c0 + p1w * c1 + p2w * c2 + p3w * c3;
        m = m_new;
        // never-valid group: m stays NEG, p == 1, acc accumulates real rows —
        // cancelled exactly at merge by weight exp(NEG - M) == 0.
    }

    // merge the 8 group states: M = max m_k; out = sum exp(m_k-M)*acc_k / sum exp(m_k-M)*l_k
    red[rg][c] = acc;
    if (c == 0) { mred[rg] = m; lred[rg] = l; }
    __syncthreads();
    if (rg == 0) {
        float M = mred[0];
        #pragma unroll
        for (int k = 1; k < 8; ++k) M = fmaxf(M, mred[k]);
        f4 r = {0.f, 0.f, 0.f, 0.f};
        float ltot = 0.0f;
        #pragma unroll
        for (int k = 0; k < 8; ++k) {
            float wgt = __expf(mred[k] - M);
            ltot += lred[k] * wgt;
            r += wgt * red[k][c];
        }
        float invl = 1.0f / ltot;            // len > 0: group with global max has wgt 1, l >= 1
        r *= invl;
        ((f4*)out)[g * 32 + c] = r;
    }
}

// ---------------- launch ----------------
extern "C" void kernel_launch(void* const* d_in, const int* in_sizes, int n_in,
                              void* d_out, int out_size, void* d_ws, size_t ws_size,
                              hipStream_t stream) {
    const float* feat = (const float*)d_in[0];
    const float* gw   = (const float*)d_in[1];
    const float* gb   = (const float*)d_in[2];
    const int*   seg  = (const int*)d_in[3];
    int N = in_sizes[0] / DD;                        // 500000

    fused_kernel<<<NSEG, 256, 0, stream>>>(feat, gw, gb, seg, N, (float*)d_out);
}